// Round 1
// baseline (206.998 us; speedup 1.0000x reference)
//
#include <hip/hip_runtime.h>

#define DT (1.0f/60.0f)
#define G_ACC 9.81f
#define RHO 1.225f
#define CD_ 0.47f
#define NU 0.001f

__device__ __forceinline__ float softplus_f(float x) {
    return log1pf(expf(-fabsf(x))) + fmaxf(x, 0.0f);
}

// ---------------------------------------------------------------------------
// Particle kernel: one block = one batch, one thread = one particle (64/wave).
// ---------------------------------------------------------------------------
__global__ __launch_bounds__(64) void particle_kernel(
    const float* __restrict__ pos, const float* __restrict__ vel,
    const float* __restrict__ rot, const float* __restrict__ omega,
    const float* __restrict__ mass, const float* __restrict__ inertia,
    const float* __restrict__ contacts, const float* __restrict__ energy,
    const float* __restrict__ Fext, const float* __restrict__ tau,
    const float* __restrict__ log_A, const float* __restrict__ log_k,
    const float* __restrict__ log_b, float* __restrict__ out)
{
    const int b = blockIdx.x;
    const int i = threadIdx.x;   // particle index
    __shared__ float cont[64*65];        // +1 pad: row reads are 2-way (free)
    __shared__ float spos[64][3];
    __shared__ float svel[64][3];

    const float* cb = contacts + (size_t)b*64*64;
    #pragma unroll
    for (int r = 0; r < 64; ++r)
        cont[r*65 + i] = cb[r*64 + i];

    const size_t p3 = ((size_t)b*64 + i)*3;
    const size_t p4 = ((size_t)b*64 + i)*4;
    float bpx=pos[p3],   bpy=pos[p3+1],   bpz=pos[p3+2];
    float bvx=vel[p3],   bvy=vel[p3+1],   bvz=vel[p3+2];
    float brw=rot[p4],   brx=rot[p4+1],   bry=rot[p4+2],  brz=rot[p4+3];
    float box=omega[p3], boy=omega[p3+1], boz=omega[p3+2];
    float m  = mass[(size_t)b*64+i];
    float Ix=inertia[p3], Iy=inertia[p3+1], Iz=inertia[p3+2];
    float Fex=Fext[p3],   Fey=Fext[p3+1],   Fez=Fext[p3+2];
    float tx=tau[p3],     ty=tau[p3+1],     tz=tau[p3+2];
    float Ai = softplus_f(log_A[i]);
    float kc = softplus_f(log_k[0]);
    float bc = softplus_f(log_b[0]);
    float dragc = -0.5f * RHO * CD_ * Ai;
    float invm  = 1.0f / m;
    float iIx = 1.0f/fmaxf(Ix,1e-6f), iIy = 1.0f/fmaxf(Iy,1e-6f), iIz = 1.0f/fmaxf(Iz,1e-6f);

    // current stage state
    float cpx=bpx, cpy=bpy, cpz=bpz;
    float cvx=bvx, cvy=bvy, cvz=bvz;
    float crw=brw, crx=brx, cry=bry, crz=brz;
    float cox=box, coy=boy, coz=boz;

    // RK4 accumulators
    float apx=0,apy=0,apz=0, avx=0,avy=0,avz=0;
    float arw=0,arx=0,ary=0,arz=0, awx=0,awy=0,awz=0;
    float eacc=0.f;
    float k1vx=0,k1vy=0,k1vz=0;

    const float wgt[4] = {1.f, 2.f, 2.f, 1.f};
    const float hs[4]  = {DT*0.5f, DT*0.5f, DT, 0.f};

    for (int s = 0; s < 4; ++s) {
        __syncthreads();
        spos[i][0]=cpx; spos[i][1]=cpy; spos[i][2]=cpz;
        svel[i][0]=cvx; svel[i][1]=cvy; svel[i][2]=cvz;
        __syncthreads();

        float Fcx=0.f, Fcy=0.f, Fcz=0.f;
        for (int j = 0; j < 64; ++j) {
            float dx = spos[j][0]-cpx, dy = spos[j][1]-cpy, dz = spos[j][2]-cpz;
            float d2 = dx*dx + dy*dy + dz*dz;
            float dist = fmaxf(sqrtf(d2), 1e-6f);
            float pen = fmaxf(1.0f - dist, 0.0f);
            float coef = kc * pen / dist;          // k * pen * (1/dist); *d gives k*pen*n_hat
            float cbj = bc * cont[i*65 + j];
            Fcx += coef*dx + cbj*(svel[j][0]-cvx);
            Fcy += coef*dy + cbj*(svel[j][1]-cvy);
            Fcz += coef*dz + cbj*(svel[j][2]-cvz);
        }

        float vm = fmaxf(sqrtf(cvx*cvx+cvy*cvy+cvz*cvz), 1e-6f);
        float dc = dragc * vm;
        float Fdx = dc*cvx, Fdy = dc*cvy, Fdz = dc*cvz;

        float dvx = (Fex + Fdx + Fcx) * invm;
        float dvy = (Fey + Fdy + Fcy) * invm;
        float dvz = (Fez - m*G_ACC + Fdz + Fcz) * invm;

        // quaternion derivative
        float dqw = 0.5f*(-crx*cox - cry*coy - crz*coz);
        float dqx = 0.5f*( crw*cox + cry*coz - crz*coy);
        float dqy = 0.5f*( crw*coy - crx*coz + crz*cox);
        float dqz = 0.5f*( crw*coz + crx*coy - cry*cox);

        // domega = (tau - omega x (I*omega)) / max(I,1e-6)
        float Iox = Ix*cox, Ioy = Iy*coy, Ioz = Iz*coz;
        float cxv = coy*Ioz - coz*Ioy;
        float cyv = coz*Iox - cox*Ioz;
        float czv = cox*Ioy - coy*Iox;
        float dwx = (tx - cxv) * iIx;
        float dwy = (ty - cyv) * iIy;
        float dwz = (tz - czv) * iIz;

        // dE = (Fext . v) + (Fd . v), summed over particles
        float ei = (Fex+Fdx)*cvx + (Fey+Fdy)*cvy + (Fez+Fdz)*cvz;
        #pragma unroll
        for (int off = 32; off > 0; off >>= 1) ei += __shfl_xor(ei, off, 64);

        float w = wgt[s];
        eacc += w * ei;
        if (s == 0) { k1vx=dvx; k1vy=dvy; k1vz=dvz; }
        apx += w*cvx; apy += w*cvy; apz += w*cvz;
        avx += w*dvx; avy += w*dvy; avz += w*dvz;
        arw += w*dqw; arx += w*dqx; ary += w*dqy; arz += w*dqz;
        awx += w*dwx; awy += w*dwy; awz += w*dwz;

        if (s < 3) {
            float h = hs[s];
            float npx = bpx + h*cvx, npy = bpy + h*cvy, npz = bpz + h*cvz;
            cvx = bvx + h*dvx; cvy = bvy + h*dvy; cvz = bvz + h*dvz;
            cpx = npx; cpy = npy; cpz = npz;
            float qw = brw + h*dqw, qx = brx + h*dqx, qy = bry + h*dqy, qz = brz + h*dqz;
            float iqn = 1.0f / fmaxf(sqrtf(qw*qw+qx*qx+qy*qy+qz*qz), 1e-12f);
            crw = qw*iqn; crx = qx*iqn; cry = qy*iqn; crz = qz*iqn;
            cox = box + h*dwx; coy = boy + h*dwy; coz = boz + h*dwz;
        }
    }

    const float s6 = DT / 6.0f;
    float* ob = out + (size_t)b * 13313;
    ob[      i*3+0] = bpx + s6*apx;  ob[      i*3+1] = bpy + s6*apy;  ob[      i*3+2] = bpz + s6*apz;
    ob[192 + i*3+0] = bvx + s6*avx;  ob[192 + i*3+1] = bvy + s6*avy;  ob[192 + i*3+2] = bvz + s6*avz;
    {
        float qw=brw+s6*arw, qx=brx+s6*arx, qy=bry+s6*ary, qz=brz+s6*arz;
        float iq = 1.0f / fmaxf(sqrtf(qw*qw+qx*qx+qy*qy+qz*qz), 1e-12f);
        ob[384 + i*4+0]=qw*iq; ob[384 + i*4+1]=qx*iq; ob[384 + i*4+2]=qy*iq; ob[384 + i*4+3]=qz*iq;
    }
    ob[640 + i*3+0] = box + s6*awx;  ob[640 + i*3+1] = boy + s6*awy;  ob[640 + i*3+2] = boz + s6*awz;
    ob[832 + i*3+0] = Fex + m*k1vx;  ob[832 + i*3+1] = Fey + m*k1vy;  ob[832 + i*3+2] = Fez + m*k1vz;
    if (i == 0) ob[1024] = energy[b] + s6*eacc;
}

// ---------------------------------------------------------------------------
// Fluid kernel: one block = (batch, channel). Depthwise 3x3x3 conv RK4 with
// per-channel mean subtraction each stage. Thread = one (z,y) row of 16 cells.
// Row stride 20 floats: keeps float4 alignment and spreads row starts across
// LDS banks (20*idx mod 32 covers 8 groups x 4 banks).
// ---------------------------------------------------------------------------
#define RS 20

__global__ __launch_bounds__(256) void fluid_kernel(
    const float* __restrict__ fluid, const float* __restrict__ conv_w,
    float* __restrict__ out)
{
    const int b = blockIdx.x;
    const int c = blockIdx.y;
    const int t = threadIdx.x;          // 0..255
    const int z = t >> 4, y = t & 15;
    __shared__ __align__(16) float u[256*RS];
    __shared__ float wch[27];
    __shared__ float red[4];
    if (t < 27) wch[t] = conv_w[c*27 + t];

    const int cellb = t*16;             // z*256 + y*16
    const int rowb  = t*RS;             // padded LDS row base
    const float* fb = fluid + (size_t)b*12288 + c;   // stride-3 channel view

    float base[16], acc[16], kk[16];
    #pragma unroll
    for (int x = 0; x < 16; ++x) {
        float v = fb[(cellb + x)*3];
        base[x] = v; u[rowb + x] = v; acc[x] = 0.f;
    }
    __syncthreads();

    const float wgt[4] = {1.f, 2.f, 2.f, 1.f};
    const float hs[4]  = {DT*0.5f, DT*0.5f, DT, 0.f};

    for (int s = 0; s < 4; ++s) {
        float o[16];
        #pragma unroll
        for (int x = 0; x < 16; ++x) o[x] = 0.f;

        #pragma unroll
        for (int dz = -1; dz <= 1; ++dz) {
            int zz = z + dz; if (zz < 0 || zz > 15) continue;
            #pragma unroll
            for (int dy = -1; dy <= 1; ++dy) {
                int yy = y + dy; if (yy < 0 || yy > 15) continue;
                const float* rp = &u[(zz*16 + yy)*RS];
                float r[16];
                *(float4*)&r[0]  = *(const float4*)(rp + 0);
                *(float4*)&r[4]  = *(const float4*)(rp + 4);
                *(float4*)&r[8]  = *(const float4*)(rp + 8);
                *(float4*)&r[12] = *(const float4*)(rp + 12);
                const int wb = (dz+1)*9 + (dy+1)*3;
                float w0 = wch[wb], w1 = wch[wb+1], w2 = wch[wb+2];
                o[0] += w1*r[0] + w2*r[1];
                #pragma unroll
                for (int x = 1; x < 15; ++x) o[x] += w0*r[x-1] + w1*r[x] + w2*r[x+1];
                o[15] += w0*r[14] + w1*r[15];
            }
        }

        float w = wgt[s];
        #pragma unroll
        for (int x = 0; x < 16; ++x) { kk[x] = NU * o[x]; acc[x] += w * kk[x]; }

        if (s < 3) {
            float h = hs[s];
            float ps = 0.f;
            #pragma unroll
            for (int x = 0; x < 16; ++x) ps += base[x] + h*kk[x];
            #pragma unroll
            for (int off = 32; off > 0; off >>= 1) ps += __shfl_xor(ps, off, 64);
            if ((t & 63) == 0) red[t >> 6] = ps;
            __syncthreads();   // also guarantees all conv reads of u are done
            float mean = (red[0]+red[1]+red[2]+red[3]) * (1.0f/4096.0f);
            #pragma unroll
            for (int x = 0; x < 16; ++x) u[rowb + x] = base[x] + h*kk[x] - mean;
            __syncthreads();
        }
    }

    float raw[16];
    float ps = 0.f;
    #pragma unroll
    for (int x = 0; x < 16; ++x) { raw[x] = base[x] + (DT/6.0f)*acc[x]; ps += raw[x]; }
    #pragma unroll
    for (int off = 32; off > 0; off >>= 1) ps += __shfl_xor(ps, off, 64);
    if ((t & 63) == 0) red[t >> 6] = ps;
    __syncthreads();
    float mean = (red[0]+red[1]+red[2]+red[3]) * (1.0f/4096.0f);

    float* ob = out + (size_t)b*13313 + 1025 + c;
    #pragma unroll
    for (int x = 0; x < 16; ++x) ob[(cellb + x)*3] = raw[x] - mean;
}

extern "C" void kernel_launch(void* const* d_in, const int* in_sizes, int n_in,
                              void* d_out, int out_size, void* d_ws, size_t ws_size,
                              hipStream_t stream) {
    const float* pos      = (const float*)d_in[0];
    const float* vel      = (const float*)d_in[1];
    const float* rot      = (const float*)d_in[2];
    const float* omega    = (const float*)d_in[3];
    const float* mass     = (const float*)d_in[4];
    const float* inertia  = (const float*)d_in[5];
    const float* contacts = (const float*)d_in[6];
    const float* energy   = (const float*)d_in[7];
    const float* fluid_v  = (const float*)d_in[8];
    const float* Fext     = (const float*)d_in[9];
    const float* tau      = (const float*)d_in[10];
    const float* log_A    = (const float*)d_in[11];
    const float* log_k    = (const float*)d_in[12];
    const float* log_b    = (const float*)d_in[13];
    const float* conv_w   = (const float*)d_in[14];
    float* out = (float*)d_out;

    particle_kernel<<<dim3(512), dim3(64), 0, stream>>>(
        pos, vel, rot, omega, mass, inertia, contacts, energy,
        Fext, tau, log_A, log_k, log_b, out);
    fluid_kernel<<<dim3(512, 3), dim3(256), 0, stream>>>(fluid_v, conv_w, out);
}

// Round 2
// 167.046 us; speedup vs baseline: 1.2392x; 1.2392x over previous
//
#include <hip/hip_runtime.h>

#define DT (1.0f/60.0f)
#define G_ACC 9.81f
#define RHO 1.225f
#define CD_ 0.47f
#define NU 0.001f

__device__ __forceinline__ float softplus_f(float x) {
    return log1pf(expf(-fabsf(x))) + fmaxf(x, 0.0f);
}

// readlane: j must be wave-uniform (it is: q*16+jj with q uniform per wave)
#define RL(v, l) __int_as_float(__builtin_amdgcn_readlane(__float_as_int(v), (l)))

// DPP x-shifts within 16-lane rows (x = lane&15). bound_ctrl=1 -> 0 at row
// edges = exactly the conv zero padding.
__device__ __forceinline__ float dpp_xm(float v) { // value from x-1, 0 at x==0
    return __int_as_float(__builtin_amdgcn_update_dpp(0, __float_as_int(v), 0x111, 0xf, 0xf, true));
}
__device__ __forceinline__ float dpp_xp(float v) { // value from x+1, 0 at x==15
    return __int_as_float(__builtin_amdgcn_update_dpp(0, __float_as_int(v), 0x101, 0xf, 0xf, true));
}

// ---------------------------------------------------------------------------
// Particle kernel: one block = one batch. 256 threads = 4 waves; wave q
// handles contact partners j in [16q,16q+16). Lane i = particle i; neighbor
// state via v_readlane (no LDS in inner loop). Partial Fc reduced via LDS.
// ---------------------------------------------------------------------------
__global__ __launch_bounds__(256) void particle_kernel(
    const float* __restrict__ pos, const float* __restrict__ vel,
    const float* __restrict__ rot, const float* __restrict__ omega,
    const float* __restrict__ mass, const float* __restrict__ inertia,
    const float* __restrict__ contacts, const float* __restrict__ energy,
    const float* __restrict__ Fext, const float* __restrict__ tau,
    const float* __restrict__ log_A, const float* __restrict__ log_k,
    const float* __restrict__ log_b, float* __restrict__ out)
{
    const int b = blockIdx.x;
    const int t = threadIdx.x;
    const int q = t >> 6;       // j-chunk / wave id
    const int i = t & 63;       // particle id

    __shared__ float sF[2][4][192];   // [buf][q][i*3+c]; 3 odd -> conflict-free

    // contacts for (i, j in chunk) -> 16 registers (stage-invariant)
    const float* cbase = contacts + (size_t)b*4096 + (size_t)i*64 + q*16;
    float4 cA = ((const float4*)cbase)[0];
    float4 cB = ((const float4*)cbase)[1];
    float4 cC = ((const float4*)cbase)[2];
    float4 cD = ((const float4*)cbase)[3];
    float cj[16] = {cA.x,cA.y,cA.z,cA.w, cB.x,cB.y,cB.z,cB.w,
                    cC.x,cC.y,cC.z,cC.w, cD.x,cD.y,cD.z,cD.w};

    const size_t p3 = ((size_t)b*64 + i)*3;
    const size_t p4 = ((size_t)b*64 + i)*4;
    float bpx=pos[p3],   bpy=pos[p3+1],   bpz=pos[p3+2];
    float bvx=vel[p3],   bvy=vel[p3+1],   bvz=vel[p3+2];
    float brw=rot[p4],   brx=rot[p4+1],   bry=rot[p4+2],  brz=rot[p4+3];
    float box=omega[p3], boy=omega[p3+1], boz=omega[p3+2];
    float m  = mass[(size_t)b*64+i];
    float Ix=inertia[p3], Iy=inertia[p3+1], Iz=inertia[p3+2];
    float Fex=Fext[p3],   Fey=Fext[p3+1],   Fez=Fext[p3+2];
    float tx=tau[p3],     ty=tau[p3+1],     tz=tau[p3+2];
    float Ai = softplus_f(log_A[i]);
    float kc = softplus_f(log_k[0]);
    float bc = softplus_f(log_b[0]);
    float dragc = -0.5f * RHO * CD_ * Ai;
    float invm  = 1.0f / m;
    float iIx = 1.0f/fmaxf(Ix,1e-6f), iIy = 1.0f/fmaxf(Iy,1e-6f), iIz = 1.0f/fmaxf(Iz,1e-6f);

    float cpx=bpx, cpy=bpy, cpz=bpz;
    float cvx=bvx, cvy=bvy, cvz=bvz;
    float crw=brw, crx=brx, cry=bry, crz=brz;
    float cox=box, coy=boy, coz=boz;

    float apx=0,apy=0,apz=0, avx=0,avy=0,avz=0;
    float arw=0,arx=0,ary=0,arz=0, awx=0,awy=0,awz=0;
    float eacc=0.f;
    float k1vx=0,k1vy=0,k1vz=0;

    const float wgt[4] = {1.f, 2.f, 2.f, 1.f};
    const float hs[4]  = {DT*0.5f, DT*0.5f, DT, 0.f};
    const int j0 = q << 4;

    for (int s = 0; s < 4; ++s) {
        float Fcx=0.f, Fcy=0.f, Fcz=0.f;
        #pragma unroll
        for (int jj = 0; jj < 16; ++jj) {
            const int j = j0 + jj;
            float pjx = RL(cpx, j), pjy = RL(cpy, j), pjz = RL(cpz, j);
            float vjx = RL(cvx, j), vjy = RL(cvy, j), vjz = RL(cvz, j);
            float dx = pjx - cpx, dy = pjy - cpy, dz = pjz - cpz;
            float d2 = dx*dx + dy*dy + dz*dz;
            float dist = fmaxf(sqrtf(d2), 1e-6f);
            float pen  = fmaxf(1.0f - dist, 0.0f);
            float coef = kc * pen * __builtin_amdgcn_rcpf(dist);
            float cbj  = bc * cj[jj];
            Fcx += coef*dx + cbj*(vjx - cvx);
            Fcy += coef*dy + cbj*(vjy - cvy);
            Fcz += coef*dz + cbj*(vjz - cvz);
        }
        const int buf = s & 1;
        sF[buf][q][i*3+0] = Fcx;
        sF[buf][q][i*3+1] = Fcy;
        sF[buf][q][i*3+2] = Fcz;
        __syncthreads();
        Fcx = sF[buf][0][i*3+0] + sF[buf][1][i*3+0] + sF[buf][2][i*3+0] + sF[buf][3][i*3+0];
        Fcy = sF[buf][0][i*3+1] + sF[buf][1][i*3+1] + sF[buf][2][i*3+1] + sF[buf][3][i*3+1];
        Fcz = sF[buf][0][i*3+2] + sF[buf][1][i*3+2] + sF[buf][2][i*3+2] + sF[buf][3][i*3+2];

        float vm = fmaxf(sqrtf(cvx*cvx+cvy*cvy+cvz*cvz), 1e-6f);
        float dc = dragc * vm;
        float Fdx = dc*cvx, Fdy = dc*cvy, Fdz = dc*cvz;

        float dvx = (Fex + Fdx + Fcx) * invm;
        float dvy = (Fey + Fdy + Fcy) * invm;
        float dvz = (Fez - m*G_ACC + Fdz + Fcz) * invm;

        float dqw = 0.5f*(-crx*cox - cry*coy - crz*coz);
        float dqx = 0.5f*( crw*cox + cry*coz - crz*coy);
        float dqy = 0.5f*( crw*coy - crx*coz + crz*cox);
        float dqz = 0.5f*( crw*coz + crx*coy - cry*cox);

        float Iox = Ix*cox, Ioy = Iy*coy, Ioz = Iz*coz;
        float cxv = coy*Ioz - coz*Ioy;
        float cyv = coz*Iox - cox*Ioz;
        float czv = cox*Ioy - coy*Iox;
        float dwx = (tx - cxv) * iIx;
        float dwy = (ty - cyv) * iIy;
        float dwz = (tz - czv) * iIz;

        float ei = (Fex+Fdx)*cvx + (Fey+Fdy)*cvy + (Fez+Fdz)*cvz;
        #pragma unroll
        for (int off = 32; off > 0; off >>= 1) ei += __shfl_xor(ei, off, 64);

        float w = wgt[s];
        eacc += w * ei;
        if (s == 0) { k1vx=dvx; k1vy=dvy; k1vz=dvz; }
        apx += w*cvx; apy += w*cvy; apz += w*cvz;
        avx += w*dvx; avy += w*dvy; avz += w*dvz;
        arw += w*dqw; arx += w*dqx; ary += w*dqy; arz += w*dqz;
        awx += w*dwx; awy += w*dwy; awz += w*dwz;

        if (s < 3) {
            float h = hs[s];
            float npx = bpx + h*cvx, npy = bpy + h*cvy, npz = bpz + h*cvz;
            cvx = bvx + h*dvx; cvy = bvy + h*dvy; cvz = bvz + h*dvz;
            cpx = npx; cpy = npy; cpz = npz;
            float qw = brw + h*dqw, qx = brx + h*dqx, qy = bry + h*dqy, qz = brz + h*dqz;
            float iqn = 1.0f / fmaxf(sqrtf(qw*qw+qx*qx+qy*qy+qz*qz), 1e-12f);
            crw = qw*iqn; crx = qx*iqn; cry = qy*iqn; crz = qz*iqn;
            cox = box + h*dwx; coy = boy + h*dwy; coz = boz + h*dwz;
        }
    }

    if (q == 0) {
        const float s6 = DT / 6.0f;
        float* ob = out + (size_t)b * 13313;
        ob[      i*3+0] = bpx + s6*apx;  ob[      i*3+1] = bpy + s6*apy;  ob[      i*3+2] = bpz + s6*apz;
        ob[192 + i*3+0] = bvx + s6*avx;  ob[192 + i*3+1] = bvy + s6*avy;  ob[192 + i*3+2] = bvz + s6*avz;
        {
            float qw=brw+s6*arw, qx=brx+s6*arx, qy=bry+s6*ary, qz=brz+s6*arz;
            float iq = 1.0f / fmaxf(sqrtf(qw*qw+qx*qx+qy*qy+qz*qz), 1e-12f);
            ob[384 + i*4+0]=qw*iq; ob[384 + i*4+1]=qx*iq; ob[384 + i*4+2]=qy*iq; ob[384 + i*4+3]=qz*iq;
        }
        ob[640 + i*3+0] = box + s6*awx;  ob[640 + i*3+1] = boy + s6*awy;  ob[640 + i*3+2] = boz + s6*awz;
        ob[832 + i*3+0] = Fex + m*k1vx;  ob[832 + i*3+1] = Fey + m*k1vy;  ob[832 + i*3+2] = Fez + m*k1vz;
        if (i == 0) ob[1024] = energy[b] + s6*eacc;
    }
}

// ---------------------------------------------------------------------------
// Fluid kernel: one block = one batch, 768 threads = 3 channels x 256 (y,x)
// z-columns. Own column in registers (z-taps free), x+-1 via DPP (bound_ctrl
// gives zero padding), y+-1 columns from LDS at odd stride 17 (conflict-free
// b32). Dense global loads/stores across the merged channels.
// ---------------------------------------------------------------------------
#define CSTR 17          // column stride in floats (odd -> bijective banks)
#define CHPL (256*CSTR)  // per-channel LDS plane (4352 floats)

__global__ __launch_bounds__(768) void fluid_kernel(
    const float* __restrict__ fluid, const float* __restrict__ conv_w,
    float* __restrict__ out)
{
    const int b   = blockIdx.x;
    const int t   = threadIdx.x;     // 0..767
    const int ch  = t >> 8;          // 0..2
    const int col = t & 255;         // y*16 + x ; x == lane&15 (DPP row-aligned)
    const int y   = col >> 4;
    const int wv  = t >> 6;          // wave id 0..11 (ch = wv>>2)

    __shared__ float u[3*CHPL];      // 52224 B
    __shared__ float wsh[81];
    __shared__ float red[12];

    if (t < 81) wsh[t] = conv_w[t];

    const int lb = ch*CHPL + col*CSTR;
    const float* fb = fluid + (size_t)b*12288 + 3*col + ch;

    float base[16], acc[16], f[16];
    #pragma unroll
    for (int z = 0; z < 16; ++z) {
        float v = fb[z*768];
        base[z] = v; f[z] = v; acc[z] = 0.f;
        u[lb + z] = v;
    }
    __syncthreads();

    const float* W = wsh + ch*27;    // W[dz*9 + dy*3 + dx] * u[z+dz-1,y+dy-1,x+dx-1]
    const int   cm = (y > 0)  ? lb - 16*CSTR : lb;
    const int   cp = (y < 15) ? lb + 16*CSTR : lb;
    const float mmask = (y > 0)  ? 1.f : 0.f;
    const float pmask = (y < 15) ? 1.f : 0.f;

    const float wgt[4] = {1.f, 2.f, 2.f, 1.f};
    const float hs[3]  = {DT*0.5f, DT*0.5f, DT};
    float mean = 0.f;

    // z-conv of column c with weight triple (W[wi], W[9+wi], W[18+wi])
    #define ACC3(c, wi) { \
        float w0_ = W[wi], w1_ = W[9+(wi)], w2_ = W[18+(wi)]; \
        _Pragma("unroll") for (int z = 0; z < 16; ++z) o[z] += w1_ * (c)[z]; \
        _Pragma("unroll") for (int z = 1; z < 16; ++z) o[z] += w0_ * (c)[z-1]; \
        _Pragma("unroll") for (int z = 0; z < 15; ++z) o[z] += w2_ * (c)[z+1]; }

    for (int s = 0; s < 4; ++s) {
        float o[16];
        #pragma unroll
        for (int z = 0; z < 16; ++z) o[z] = 0.f;

        {   // dy = 0 (own column, registers)
            float cl[16], cr[16];
            #pragma unroll
            for (int z = 0; z < 16; ++z) { cl[z] = dpp_xm(f[z]); cr[z] = dpp_xp(f[z]); }
            ACC3(f,  4);   // dx = 0
            ACC3(cl, 3);   // dx = -1
            ACC3(cr, 5);   // dx = +1
        }
        {   // dy = -1 (LDS)
            float c0[16], cl[16], cr[16];
            #pragma unroll
            for (int z = 0; z < 16; ++z) c0[z] = (u[cm + z] - mean) * mmask;
            #pragma unroll
            for (int z = 0; z < 16; ++z) { cl[z] = dpp_xm(c0[z]); cr[z] = dpp_xp(c0[z]); }
            ACC3(c0, 1);
            ACC3(cl, 0);
            ACC3(cr, 2);
        }
        {   // dy = +1 (LDS)
            float c0[16], cl[16], cr[16];
            #pragma unroll
            for (int z = 0; z < 16; ++z) c0[z] = (u[cp + z] - mean) * pmask;
            #pragma unroll
            for (int z = 0; z < 16; ++z) { cl[z] = dpp_xm(c0[z]); cr[z] = dpp_xp(c0[z]); }
            ACC3(c0, 7);
            ACC3(cl, 6);
            ACC3(cr, 8);
        }

        float w = wgt[s];
        if (s < 3) {
            float h = hs[s];
            __syncthreads();         // all reads of state s complete
            float ps = 0.f;
            #pragma unroll
            for (int z = 0; z < 16; ++z) {
                float k = NU * o[z];
                acc[z] += w * k;
                float v = base[z] + h * k;
                u[lb + z] = v;
                f[z] = v;
                ps += v;
            }
            #pragma unroll
            for (int off = 32; off > 0; off >>= 1) ps += __shfl_xor(ps, off, 64);
            if ((t & 63) == 0) red[wv] = ps;
            __syncthreads();
            mean = (red[(ch<<2)] + red[(ch<<2)+1] + red[(ch<<2)+2] + red[(ch<<2)+3]) * (1.0f/4096.0f);
            #pragma unroll
            for (int z = 0; z < 16; ++z) f[z] -= mean;
        } else {
            #pragma unroll
            for (int z = 0; z < 16; ++z) acc[z] += w * NU * o[z];
        }
    }

    // epilogue: raw = base + DT/6 * acc, subtract per-channel mean, store dense
    float raw[16];
    float ps = 0.f;
    #pragma unroll
    for (int z = 0; z < 16; ++z) { raw[z] = base[z] + (DT/6.0f)*acc[z]; ps += raw[z]; }
    #pragma unroll
    for (int off = 32; off > 0; off >>= 1) ps += __shfl_xor(ps, off, 64);
    __syncthreads();                 // protect red from stage-2 readers
    if ((t & 63) == 0) red[wv] = ps;
    __syncthreads();
    mean = (red[(ch<<2)] + red[(ch<<2)+1] + red[(ch<<2)+2] + red[(ch<<2)+3]) * (1.0f/4096.0f);

    float* ob = out + (size_t)b*13313 + 1025 + 3*col + ch;
    #pragma unroll
    for (int z = 0; z < 16; ++z) ob[z*768] = raw[z] - mean;
}

extern "C" void kernel_launch(void* const* d_in, const int* in_sizes, int n_in,
                              void* d_out, int out_size, void* d_ws, size_t ws_size,
                              hipStream_t stream) {
    const float* pos      = (const float*)d_in[0];
    const float* vel      = (const float*)d_in[1];
    const float* rot      = (const float*)d_in[2];
    const float* omega    = (const float*)d_in[3];
    const float* mass     = (const float*)d_in[4];
    const float* inertia  = (const float*)d_in[5];
    const float* contacts = (const float*)d_in[6];
    const float* energy   = (const float*)d_in[7];
    const float* fluid_v  = (const float*)d_in[8];
    const float* Fext     = (const float*)d_in[9];
    const float* tau      = (const float*)d_in[10];
    const float* log_A    = (const float*)d_in[11];
    const float* log_k    = (const float*)d_in[12];
    const float* log_b    = (const float*)d_in[13];
    const float* conv_w   = (const float*)d_in[14];
    float* out = (float*)d_out;

    particle_kernel<<<dim3(512), dim3(256), 0, stream>>>(
        pos, vel, rot, omega, mass, inertia, contacts, energy,
        Fext, tau, log_A, log_k, log_b, out);
    fluid_kernel<<<dim3(512), dim3(768), 0, stream>>>(fluid_v, conv_w, out);
}

// Round 3
// 158.736 us; speedup vs baseline: 1.3040x; 1.0523x over previous
//
#include <hip/hip_runtime.h>

#define DT (1.0f/60.0f)
#define G_ACC 9.81f
#define RHO 1.225f
#define CD_ 0.47f
#define NU 0.001f

__device__ __forceinline__ float softplus_f(float x) {
    return log1pf(expf(-fabsf(x))) + fmaxf(x, 0.0f);
}

// readlane: lane index is wave-uniform (q*16+jj, q uniform per wave)
#define RL(v, l) __int_as_float(__builtin_amdgcn_readlane(__float_as_int(v), (l)))

// DPP x-shifts within 16-lane rows (x = lane&15). bound_ctrl=1 -> 0 at row
// edges = exactly the conv zero padding. (validated in R2)
__device__ __forceinline__ float dpp_xm(float v) { // value from x-1, 0 at x==0
    return __int_as_float(__builtin_amdgcn_update_dpp(0, __float_as_int(v), 0x111, 0xf, 0xf, true));
}
__device__ __forceinline__ float dpp_xp(float v) { // value from x+1, 0 at x==15
    return __int_as_float(__builtin_amdgcn_update_dpp(0, __float_as_int(v), 0x101, 0xf, 0xf, true));
}

// ---------------------------------------------------------------------------
// Fused kernel. grid = 2048 x 256 threads.
//   blocks [0,1536):  fluid, ch = blk>>9, b = blk&511  (siblings same XCD)
//   blocks [1536,2048): particle, b = blk-1536
// ---------------------------------------------------------------------------
__global__ __launch_bounds__(256) void fused_kernel(
    const float* __restrict__ pos, const float* __restrict__ vel,
    const float* __restrict__ rot, const float* __restrict__ omega,
    const float* __restrict__ mass, const float* __restrict__ inertia,
    const float* __restrict__ contacts, const float* __restrict__ energy,
    const float* __restrict__ fluid, const float* __restrict__ Fext,
    const float* __restrict__ tau, const float* __restrict__ log_A,
    const float* __restrict__ log_k, const float* __restrict__ log_b,
    const float* __restrict__ conv_w, float* __restrict__ out)
{
    __shared__ float smem[4384];     // fluid: u[4352]+wch[27]+red[4]; particle: sF[1536]
    const int t = threadIdx.x;

    if (blockIdx.x < 1536) {
        // ================= FLUID =================
        const int b  = blockIdx.x & 511;
        const int ch = blockIdx.x >> 9;
        const int x  = t & 15, y = t >> 4, wv = t >> 6;
        float* u   = smem;           // col*17 + z, stride 17 -> conflict-free
        float* wch = smem + 4352;
        float* red = smem + 4380;
        if (t < 27) wch[t] = conv_w[ch*27 + t];

        const int lb = t*17;
        const float* fb = fluid + (size_t)b*12288 + 3*t + ch;
        float base[16], acc[16];
        #pragma unroll
        for (int z = 0; z < 16; ++z) {
            float v = fb[z*768];
            base[z] = v; acc[z] = 0.f; u[lb + z] = v;
        }
        __syncthreads();

        const float mm = (y > 0)  ? 1.f : 0.f;
        const float pm = (y < 15) ? 1.f : 0.f;
        const float xm = (x > 0)  ? 1.f : 0.f;
        const float xp = (x < 15) ? 1.f : 0.f;
        const int   cm = (y > 0)  ? lb - 272 : lb;   // 16*17
        const int   cp = (y < 15) ? lb + 272 : lb;

        // valid-tap weight sums for mean folding: conv(w-mean) = conv(w) - mean*S
        float Sdz[3];
        #pragma unroll
        for (int dz = 0; dz < 3; ++dz) {
            float a0 = wch[dz*9+0]*xm + wch[dz*9+1] + wch[dz*9+2]*xp;   // dy=-1
            float a1 = wch[dz*9+3]*xm + wch[dz*9+4] + wch[dz*9+5]*xp;   // dy= 0
            float a2 = wch[dz*9+6]*xm + wch[dz*9+7] + wch[dz*9+8]*xp;   // dy=+1
            Sdz[dz] = mm*a0 + a1 + pm*a2;
        }
        const float SzLo  = Sdz[1] + Sdz[2];            // z == 0
        const float SzMid = Sdz[0] + Sdz[1] + Sdz[2];   // 0 < z < 15
        const float SzHi  = Sdz[0] + Sdz[1];            // z == 15
        const float* W = wch + 0;    // channel weights already selected

        const float wgt[4] = {1.f, 2.f, 2.f, 1.f};
        const float hs[3]  = {DT*0.5f, DT*0.5f, DT};
        float mean = 0.f;

        #define ACC3(c, wi) { \
            float w0_ = W[wi], w1_ = W[9+(wi)], w2_ = W[18+(wi)]; \
            _Pragma("unroll") for (int z = 0; z < 16; ++z) o[z] += w1_ * (c)[z]; \
            _Pragma("unroll") for (int z = 1; z < 16; ++z) o[z] += w0_ * (c)[z-1]; \
            _Pragma("unroll") for (int z = 0; z < 15; ++z) o[z] += w2_ * (c)[z+1]; }

        for (int s = 0; s < 4; ++s) {
            float o[16];
            #pragma unroll
            for (int z = 0; z < 16; ++z) o[z] = 0.f;

            {   // dy = 0 (own column from LDS)
                float c0[16], cl[16], cr[16];
                #pragma unroll
                for (int z = 0; z < 16; ++z) c0[z] = u[lb + z];
                #pragma unroll
                for (int z = 0; z < 16; ++z) { cl[z] = dpp_xm(c0[z]); cr[z] = dpp_xp(c0[z]); }
                ACC3(c0, 4); ACC3(cl, 3); ACC3(cr, 5);
            }
            {   // dy = -1
                float c0[16], cl[16], cr[16];
                #pragma unroll
                for (int z = 0; z < 16; ++z) c0[z] = u[cm + z] * mm;
                #pragma unroll
                for (int z = 0; z < 16; ++z) { cl[z] = dpp_xm(c0[z]); cr[z] = dpp_xp(c0[z]); }
                ACC3(c0, 1); ACC3(cl, 0); ACC3(cr, 2);
            }
            {   // dy = +1
                float c0[16], cl[16], cr[16];
                #pragma unroll
                for (int z = 0; z < 16; ++z) c0[z] = u[cp + z] * pm;
                #pragma unroll
                for (int z = 0; z < 16; ++z) { cl[z] = dpp_xm(c0[z]); cr[z] = dpp_xp(c0[z]); }
                ACC3(c0, 7); ACC3(cl, 6); ACC3(cr, 8);
            }

            float w = wgt[s];
            if (s < 3) {
                float h = hs[s], ps = 0.f, wn[16];
                #pragma unroll
                for (int z = 0; z < 16; ++z) {
                    float Sz = (z == 0) ? SzLo : ((z == 15) ? SzHi : SzMid);
                    float k = NU * (o[z] - mean * Sz);
                    acc[z] += w * k;
                    wn[z] = base[z] + h * k;
                    ps += wn[z];
                }
                #pragma unroll
                for (int off = 32; off > 0; off >>= 1) ps += __shfl_xor(ps, off, 64);
                __syncthreads();            // WAR: all conv reads of state s done
                #pragma unroll
                for (int z = 0; z < 16; ++z) u[lb + z] = wn[z];
                if ((t & 63) == 0) red[wv] = ps;
                __syncthreads();            // writes + red visible
                mean = (red[0] + red[1] + red[2] + red[3]) * (1.0f/4096.0f);
            } else {
                #pragma unroll
                for (int z = 0; z < 16; ++z) {
                    float Sz = (z == 0) ? SzLo : ((z == 15) ? SzHi : SzMid);
                    acc[z] += w * NU * (o[z] - mean * Sz);
                }
            }
        }
        #undef ACC3

        float raw[16], ps = 0.f;
        #pragma unroll
        for (int z = 0; z < 16; ++z) { raw[z] = base[z] + (DT/6.0f)*acc[z]; ps += raw[z]; }
        #pragma unroll
        for (int off = 32; off > 0; off >>= 1) ps += __shfl_xor(ps, off, 64);
        __syncthreads();                    // WAR on red vs stage-2 mean reads
        if ((t & 63) == 0) red[wv] = ps;
        __syncthreads();
        float mn = (red[0] + red[1] + red[2] + red[3]) * (1.0f/4096.0f);

        float* ob = out + (size_t)b*13313 + 1025 + 3*t + ch;
        #pragma unroll
        for (int z = 0; z < 16; ++z) ob[z*768] = raw[z] - mn;
        return;
    }

    // ================= PARTICLE =================
    const int b = blockIdx.x - 1536;
    const int q = t >> 6;       // j-chunk / wave id
    const int i = t & 63;       // particle id
    // sF[buf][q][i*3+c] -> smem[buf*768 + q*192 + i*3+c]
    #define SF(buf, qq, idx) smem[(buf)*768 + (qq)*192 + (idx)]

    const float* cbase = contacts + (size_t)b*4096 + (size_t)i*64 + q*16;
    float4 cA = ((const float4*)cbase)[0];
    float4 cB = ((const float4*)cbase)[1];
    float4 cC = ((const float4*)cbase)[2];
    float4 cD = ((const float4*)cbase)[3];
    float cj[16] = {cA.x,cA.y,cA.z,cA.w, cB.x,cB.y,cB.z,cB.w,
                    cC.x,cC.y,cC.z,cC.w, cD.x,cD.y,cD.z,cD.w};

    const size_t p3 = ((size_t)b*64 + i)*3;
    const size_t p4 = ((size_t)b*64 + i)*4;
    float bpx=pos[p3],   bpy=pos[p3+1],   bpz=pos[p3+2];
    float bvx=vel[p3],   bvy=vel[p3+1],   bvz=vel[p3+2];
    float brw=rot[p4],   brx=rot[p4+1],   bry=rot[p4+2],  brz=rot[p4+3];
    float box=omega[p3], boy=omega[p3+1], boz=omega[p3+2];
    float m  = mass[(size_t)b*64+i];
    float Ix=inertia[p3], Iy=inertia[p3+1], Iz=inertia[p3+2];
    float Fex=Fext[p3],   Fey=Fext[p3+1],   Fez=Fext[p3+2];
    float tx=tau[p3],     ty=tau[p3+1],     tz=tau[p3+2];
    float Ai = softplus_f(log_A[i]);
    float kc = softplus_f(log_k[0]);
    float bc = softplus_f(log_b[0]);
    float dragc = -0.5f * RHO * CD_ * Ai;
    float invm  = 1.0f / m;
    float iIx = 1.0f/fmaxf(Ix,1e-6f), iIy = 1.0f/fmaxf(Iy,1e-6f), iIz = 1.0f/fmaxf(Iz,1e-6f);

    float cpx=bpx, cpy=bpy, cpz=bpz;
    float cvx=bvx, cvy=bvy, cvz=bvz;
    float crw=brw, crx=brx, cry=bry, crz=brz;
    float cox=box, coy=boy, coz=boz;

    float apx=0,apy=0,apz=0, avx=0,avy=0,avz=0;
    float arw=0,arx=0,ary=0,arz=0, awx=0,awy=0,awz=0;
    float eacc=0.f;
    float k1vx=0,k1vy=0,k1vz=0;

    const float wgt[4] = {1.f, 2.f, 2.f, 1.f};
    const float hs[4]  = {DT*0.5f, DT*0.5f, DT, 0.f};
    const int j0 = q << 4;

    for (int s = 0; s < 4; ++s) {
        float Fcx=0.f, Fcy=0.f, Fcz=0.f;
        #pragma unroll
        for (int jj = 0; jj < 16; ++jj) {
            const int j = j0 + jj;
            float pjx = RL(cpx, j), pjy = RL(cpy, j), pjz = RL(cpz, j);
            float vjx = RL(cvx, j), vjy = RL(cvy, j), vjz = RL(cvz, j);
            float dx = pjx - cpx, dy = pjy - cpy, dz = pjz - cpz;
            float d2 = dx*dx + dy*dy + dz*dz;
            float dist = fmaxf(sqrtf(d2), 1e-6f);
            float pen  = fmaxf(1.0f - dist, 0.0f);
            float coef = kc * pen * __builtin_amdgcn_rcpf(dist);
            float cbj  = bc * cj[jj];
            Fcx += coef*dx + cbj*(vjx - cvx);
            Fcy += coef*dy + cbj*(vjy - cvy);
            Fcz += coef*dz + cbj*(vjz - cvz);
        }
        const int buf = s & 1;
        SF(buf, q, i*3+0) = Fcx;
        SF(buf, q, i*3+1) = Fcy;
        SF(buf, q, i*3+2) = Fcz;
        __syncthreads();
        Fcx = SF(buf,0,i*3+0) + SF(buf,1,i*3+0) + SF(buf,2,i*3+0) + SF(buf,3,i*3+0);
        Fcy = SF(buf,0,i*3+1) + SF(buf,1,i*3+1) + SF(buf,2,i*3+1) + SF(buf,3,i*3+1);
        Fcz = SF(buf,0,i*3+2) + SF(buf,1,i*3+2) + SF(buf,2,i*3+2) + SF(buf,3,i*3+2);

        float vm = fmaxf(sqrtf(cvx*cvx+cvy*cvy+cvz*cvz), 1e-6f);
        float dc = dragc * vm;
        float Fdx = dc*cvx, Fdy = dc*cvy, Fdz = dc*cvz;

        float dvx = (Fex + Fdx + Fcx) * invm;
        float dvy = (Fey + Fdy + Fcy) * invm;
        float dvz = (Fez - m*G_ACC + Fdz + Fcz) * invm;

        float dqw = 0.5f*(-crx*cox - cry*coy - crz*coz);
        float dqx = 0.5f*( crw*cox + cry*coz - crz*coy);
        float dqy = 0.5f*( crw*coy - crx*coz + crz*cox);
        float dqz = 0.5f*( crw*coz + crx*coy - cry*cox);

        float Iox = Ix*cox, Ioy = Iy*coy, Ioz = Iz*coz;
        float cxv = coy*Ioz - coz*Ioy;
        float cyv = coz*Iox - cox*Ioz;
        float czv = cox*Ioy - coy*Iox;
        float dwx = (tx - cxv) * iIx;
        float dwy = (ty - cyv) * iIy;
        float dwz = (tz - czv) * iIz;

        float ei = (Fex+Fdx)*cvx + (Fey+Fdy)*cvy + (Fez+Fdz)*cvz;
        #pragma unroll
        for (int off = 32; off > 0; off >>= 1) ei += __shfl_xor(ei, off, 64);

        float w = wgt[s];
        eacc += w * ei;
        if (s == 0) { k1vx=dvx; k1vy=dvy; k1vz=dvz; }
        apx += w*cvx; apy += w*cvy; apz += w*cvz;
        avx += w*dvx; avy += w*dvy; avz += w*dvz;
        arw += w*dqw; arx += w*dqx; ary += w*dqy; arz += w*dqz;
        awx += w*dwx; awy += w*dwy; awz += w*dwz;

        if (s < 3) {
            float h = hs[s];
            float npx = bpx + h*cvx, npy = bpy + h*cvy, npz = bpz + h*cvz;
            cvx = bvx + h*dvx; cvy = bvy + h*dvy; cvz = bvz + h*dvz;
            cpx = npx; cpy = npy; cpz = npz;
            float qw = brw + h*dqw, qx = brx + h*dqx, qy = bry + h*dqy, qz = brz + h*dqz;
            float iqn = 1.0f / fmaxf(sqrtf(qw*qw+qx*qx+qy*qy+qz*qz), 1e-12f);
            crw = qw*iqn; crx = qx*iqn; cry = qy*iqn; crz = qz*iqn;
            cox = box + h*dwx; coy = boy + h*dwy; coz = boz + h*dwz;
        }
    }

    if (q == 0) {
        const float s6 = DT / 6.0f;
        float* ob = out + (size_t)b * 13313;
        ob[      i*3+0] = bpx + s6*apx;  ob[      i*3+1] = bpy + s6*apy;  ob[      i*3+2] = bpz + s6*apz;
        ob[192 + i*3+0] = bvx + s6*avx;  ob[192 + i*3+1] = bvy + s6*avy;  ob[192 + i*3+2] = bvz + s6*avz;
        {
            float qw=brw+s6*arw, qx=brx+s6*arx, qy=bry+s6*ary, qz=brz+s6*arz;
            float iq = 1.0f / fmaxf(sqrtf(qw*qw+qx*qx+qy*qy+qz*qz), 1e-12f);
            ob[384 + i*4+0]=qw*iq; ob[384 + i*4+1]=qx*iq; ob[384 + i*4+2]=qy*iq; ob[384 + i*4+3]=qz*iq;
        }
        ob[640 + i*3+0] = box + s6*awx;  ob[640 + i*3+1] = boy + s6*awy;  ob[640 + i*3+2] = boz + s6*awz;
        ob[832 + i*3+0] = Fex + m*k1vx;  ob[832 + i*3+1] = Fey + m*k1vy;  ob[832 + i*3+2] = Fez + m*k1vz;
        if (i == 0) ob[1024] = energy[b] + s6*eacc;
    }
    #undef SF
}

extern "C" void kernel_launch(void* const* d_in, const int* in_sizes, int n_in,
                              void* d_out, int out_size, void* d_ws, size_t ws_size,
                              hipStream_t stream) {
    const float* pos      = (const float*)d_in[0];
    const float* vel      = (const float*)d_in[1];
    const float* rot      = (const float*)d_in[2];
    const float* omega    = (const float*)d_in[3];
    const float* mass     = (const float*)d_in[4];
    const float* inertia  = (const float*)d_in[5];
    const float* contacts = (const float*)d_in[6];
    const float* energy   = (const float*)d_in[7];
    const float* fluid_v  = (const float*)d_in[8];
    const float* Fext     = (const float*)d_in[9];
    const float* tau      = (const float*)d_in[10];
    const float* log_A    = (const float*)d_in[11];
    const float* log_k    = (const float*)d_in[12];
    const float* log_b    = (const float*)d_in[13];
    const float* conv_w   = (const float*)d_in[14];
    float* out = (float*)d_out;

    fused_kernel<<<dim3(2048), dim3(256), 0, stream>>>(
        pos, vel, rot, omega, mass, inertia, contacts, energy, fluid_v,
        Fext, tau, log_A, log_k, log_b, conv_w, out);
}